// Round 21
// baseline (236.425 us; speedup 1.0000x reference)
//
#include <hip/hip_runtime.h>

typedef short short8  __attribute__((ext_vector_type(8)));
typedef float f32x4   __attribute__((ext_vector_type(4)));

#define B_TOTAL 4096
#define T_STEPS 512
#define F_IN    32
#define H_DIM   60
#define KW      92      // F + H
#define BC      16      // batch rows per block
#define HPITCH  72      // h-LDS row pitch in halves (144B rows, 2-way-free)

#define MFMA(A, B, C) __builtin_amdgcn_mfma_f32_16x16x32_bf16((A), (B), (C), 0, 0, 0)

__device__ __forceinline__ unsigned short bf16rne(float f) {
    unsigned int u = __float_as_uint(f);
    u += 0x7FFFu + ((u >> 16) & 1u);
    return (unsigned short)(u >> 16);
}
__device__ __forceinline__ float rcpf(float z) {
    return __builtin_amdgcn_rcpf(z);            // v_rcp_f32, 1 ulp
}
__device__ __forceinline__ float exp2f_(float z) {
#if __has_builtin(__builtin_amdgcn_exp2f)
    return __builtin_amdgcn_exp2f(z);           // v_exp_f32
#else
    float r; asm("v_exp_f32 %0, %1" : "=v"(r) : "v"(z)); return r;
#endif
}

// LDS-visibility barrier WITHOUT the vmcnt(0) drain __syncthreads() imposes:
// outstanding global loads (x prefetch) stay in flight across it.
#define BAR()                                                                   \
    {                                                                           \
        asm volatile("s_waitcnt lgkmcnt(0)" ::: "memory");                      \
        __builtin_amdgcn_sched_barrier(0);                                      \
        __builtin_amdgcn_s_barrier();                                           \
        __builtin_amdgcn_sched_barrier(0);                                      \
    }

// float4 pair -> packed bf16 short8 fragment, RNE, via v_cvt_pk_bf16_f32
#define CVTH(VA, VB, OH)                                                        \
    {                                                                           \
        int4 hp;                                                                \
        asm("v_cvt_pk_bf16_f32 %0, %1, %2" : "=v"(hp.x) : "v"((VA).x), "v"((VA).y)); \
        asm("v_cvt_pk_bf16_f32 %0, %1, %2" : "=v"(hp.y) : "v"((VA).z), "v"((VA).w)); \
        asm("v_cvt_pk_bf16_f32 %0, %1, %2" : "=v"(hp.z) : "v"((VB).x), "v"((VB).y)); \
        asm("v_cvt_pk_bf16_f32 %0, %1, %2" : "=v"(hp.w) : "v"((VB).z), "v"((VB).w)); \
        OH = __builtin_bit_cast(short8, hp);                                    \
    }

// Paired LSTM cell update, UNMERGED reciprocals (latency-bound regime: the
// cross-unit rcp-merge traded +16cy of dependent chain for -2 rcp issues —
// wrong direction now). Pre-activations pre-scaled: i,f,o by log2e; j by
// 2*log2e; forget +1 bias folded. 10 exp2 + 6 rcp per pair, minimal chain.
#define CELL2(P, Q, H0, H1)                                                     \
    float h0, h1;                                                               \
    {                                                                           \
        float ei0 = exp2f_(-P[0]), ei1 = exp2f_(-Q[0]);                         \
        float qj0 = exp2f_(P[1]),  qj1 = exp2f_(Q[1]);                          \
        float ef0 = exp2f_(-P[2]), ef1 = exp2f_(-Q[2]);                         \
        float eo0 = exp2f_(-P[3]), eo1 = exp2f_(-Q[3]);                         \
        float fg0 = rcpf(1.0f + ef0), fg1 = rcpf(1.0f + ef1);                   \
        float pr0 = (qj0 - 1.0f) * rcpf((1.0f + ei0) * (qj0 + 1.0f));           \
        float pr1 = (qj1 - 1.0f) * rcpf((1.0f + ei1) * (qj1 + 1.0f));           \
        cst0 = cst0 * fg0 + pr0;                                                \
        cst1 = cst1 * fg1 + pr1;                                                \
        float zc0 = __builtin_amdgcn_fmed3f(cst0 * (2.0f * 1.44269504088896340736f), -126.0f, 126.0f); \
        float zc1 = __builtin_amdgcn_fmed3f(cst1 * (2.0f * 1.44269504088896340736f), -126.0f, 126.0f); \
        float qc0 = exp2f_(zc0), qc1 = exp2f_(zc1);                             \
        H0 = (qc0 - 1.0f) * rcpf((qc0 + 1.0f) * (1.0f + eo0));                  \
        H1 = (qc1 - 1.0f) * rcpf((qc1 + 1.0f) * (1.0f + eo1));                  \
    }

__global__ __launch_bounds__(512, 2)
void lstm_mfma_kernel(const float* __restrict__ x,
                      const float* __restrict__ wk,
                      const float* __restrict__ bias,
                      const float* __restrict__ dense_w,
                      const float* __restrict__ dense_b,
                      float* __restrict__ out)
{
    // Double-buffered h-state, bf16, PAIR-PERMUTED columns: h of units
    // (8w+kg, 8w+4+kg) lives at cols (2m, 2m+1), m = 4w+kg. Weights' K-order
    // is gathered with the same permutation, so MFMA semantics are unchanged.
    __shared__ __align__(16) short Hhi[2][BC][HPITCH];
    __shared__ float Hf[BC][64];            // final-step h, f32, old unit order

    const int tid  = threadIdx.x;
    const int lane = tid & 63;
    const int w    = tid >> 6;              // wave 0..7
    const int b0   = blockIdx.x * BC;
    const int lm   = lane & 15;             // batch row (B-operand N index)
    const int kg   = lane >> 4;             // K octet group 0..3
    const int lk8  = kg * 8;

    const float LOG2E = 1.44269504088896340736f;

    // ---------------- A fragments = W^T (static), exp2-prescaled, bf16 ------
    short8 wh[2][3];
    f32x4  biasv[2];
    #pragma unroll
    for (int tt = 0; tt < 2; ++tt) {
        const int mt = 2 * w + tt;
        if (mt < 15) {
            const int uo = 4 * mt + kg;
            f32x4 bv;
            #pragma unroll
            for (int r = 0; r < 4; ++r) {
                const float sc = (r == 1) ? 2.0f * LOG2E : LOG2E;
                bv[r] = (bias[r * 60 + uo] + (r == 2 ? 1.0f : 0.0f)) * sc;
            }
            biasv[tt] = bv;
            const int c = 16 * mt + lm;          // A-operand M-row
            const int u = c >> 2, g = c & 3;
            const float gsc = (g == 1) ? 2.0f * LOG2E : LOG2E;
            // s = 0: x K-step, direct k order
            {
                short8 hv;
                #pragma unroll
                for (int e = 0; e < 8; ++e)
                    hv[e] = (short)bf16rne(wk[(lk8 + e) * 240 + g * 60 + u] * gsc);
                wh[tt][0] = hv;
            }
            // s = 1,2: h K-steps, pair-permuted column order
            #pragma unroll
            for (int s = 1; s < 3; ++s) {
                short8 hv;
                #pragma unroll
                for (int e = 0; e < 8; ++e) {
                    const int cc = (s - 1) * 32 + lk8 + e;   // permuted col
                    const int m  = cc >> 1, bit = cc & 1;
                    const int uk = 8 * (m >> 2) + 4 * bit + (m & 3);
                    float wv = (uk < H_DIM) ? wk[(F_IN + uk) * 240 + g * 60 + u] * gsc : 0.0f;
                    hv[e] = (short)bf16rne(wv);
                }
                wh[tt][s] = hv;
            }
        } else {
            biasv[tt] = (f32x4){0.f, 0.f, 0.f, 0.f};
            #pragma unroll
            for (int s = 0; s < 3; ++s) wh[tt][s] = (short8)0;
        }
    }
    const int u0 = 8 * w + kg;              // unit of tile mt0 output (old order)
    const int u1 = 8 * w + 4 + kg;          // unit of tile mt1 output
    const int mIdx = 4 * w + kg;            // packed-pair column index
    const bool t1ok = (2 * w + 1 < 15);

    // ---------------- zero h buffers (h0 = 0, pad cols = 0) -----------------
    for (int i = tid; i < 2 * BC * HPITCH; i += 512)
        (&Hhi[0][0][0])[i] = 0;

    // ---------------- x fragments: lane owns (row lm, k lk8..lk8+7) ---------
    const float* xrow = x + (size_t)(b0 + lm) * (T_STEPS * F_IN) + lk8;
    // slot A <- x(0), slot B <- x(1); conversion happens post-barrier in-step
    float4 sAa = *reinterpret_cast<const float4*>(xrow);
    float4 sAb = *reinterpret_cast<const float4*>(xrow + 4);
    float4 sBa = *reinterpret_cast<const float4*>(xrow + 1 * F_IN);
    float4 sBb = *reinterpret_cast<const float4*>(xrow + 1 * F_IN + 4);
    short8 axh;
    const float* xp2 = xrow + 2 * F_IN;     // bumped by 2*F_IN per step-pair

    float cst0 = 0.f, cst1 = 0.f;           // cell state for (b=lm, u0/u1)
    const f32x4 z4 = {0.f, 0.f, 0.f, 0.f};
    __syncthreads();                        // (drains vmcnt: x0/x1 landed)

// One LSTM step. PARALLEL h-MFMA chains: the s2-MFMA issues right after the
// uh2 read on its own chain (read-path = read -> 1 MFMA -> add, was 2 MFMAs);
// s1 chains off the x-partial. CVTH post-barrier covers ds_read latency.
// setprio(1) de-phases the 2 waves/SIMD (R17-proven). Raw barrier: lgkm only;
// the 2 outstanding x prefetch loads stay in flight across it.
#define STEPX(CUR, NXT, DOLOAD, SA, SB, XOFF, LASTF)                            \
    {                                                                           \
        short8 uh1 = *reinterpret_cast<const short8*>(&Hhi[CUR][lm][lk8]);      \
        short8 uh2 = *reinterpret_cast<const short8*>(&Hhi[CUR][lm][32 + lk8]); \
        CVTH(SA, SB, axh)                                                       \
        if (DOLOAD) {                                                           \
            SA = *reinterpret_cast<const float4*>(xp2 + (XOFF));                \
            SB = *reinterpret_cast<const float4*>(xp2 + (XOFF) + 4);            \
        }                                                                       \
        __builtin_amdgcn_s_setprio(1);                                          \
        f32x4 p1 = MFMA(wh[0][0], axh, biasv[0]);                               \
        f32x4 q1 = MFMA(wh[1][0], axh, biasv[1]);                               \
        f32x4 p2 = MFMA(wh[0][2], uh2, z4);                                     \
        f32x4 q2 = MFMA(wh[1][2], uh2, z4);                                     \
        p1 = MFMA(wh[0][1], uh1, p1);                                           \
        q1 = MFMA(wh[1][1], uh1, q1);                                           \
        __builtin_amdgcn_s_setprio(0);                                          \
        f32x4 p = p1 + p2;                                                      \
        f32x4 q = q1 + q2;                                                      \
        CELL2(p, q, h0, h1)                                                     \
        int pk;                                                                 \
        asm("v_cvt_pk_bf16_f32 %0, %1, %2" : "=v"(pk) : "v"(h0), "v"(h1));      \
        if (LASTF) {                                                            \
            Hf[lm][u0] = h0;                                                    \
            if (t1ok) Hf[lm][u1] = h1;                                          \
        } else {                                                                \
            *reinterpret_cast<int*>(&Hhi[NXT][lm][2 * mIdx]) = pk;              \
        }                                                                       \
        BAR()                                                                   \
    }

    for (int t = 0; t < T_STEPS - 2; t += 2) {
        STEPX(0, 1, 1, sAa, sAb, 0,    0)   // cvt x(t)  <-A, load x(t+2)->A
        STEPX(1, 0, 1, sBa, sBb, F_IN, 0)   // cvt x(t+1)<-B, load x(t+3)->B
        xp2 += 2 * F_IN;
    }
    // tail: t = 510 (cvt x(510) from A, no load), t = 511 (cvt x(511) from B,
    // LAST -> Hf)
    STEPX(0, 1, 0, sAa, sAb, 0, 0)
    STEPX(1, 0, 0, sBa, sBb, 0, 1)

    // ---------------- epilogue: out[b] = h . dense_w + dense_b --------------
    if (tid < BC) {
        float acc = dense_b[0];
        #pragma unroll 4
        for (int uu = 0; uu < H_DIM; ++uu)
            acc = fmaf(Hf[tid][uu], dense_w[uu], acc);
        out[b0 + tid] = acc;
    }
}

extern "C" void kernel_launch(void* const* d_in, const int* in_sizes, int n_in,
                              void* d_out, int out_size, void* d_ws, size_t ws_size,
                              hipStream_t stream) {
    const float* x       = (const float*)d_in[0];
    const float* wk      = (const float*)d_in[1];
    const float* bias    = (const float*)d_in[2];
    const float* dense_w = (const float*)d_in[3];
    const float* dense_b = (const float*)d_in[4];
    float* out = (float*)d_out;

    lstm_mfma_kernel<<<B_TOTAL / BC, 512, 0, stream>>>(
        x, wk, bias, dense_w, dense_b, out);
}